// Round 6
// baseline (658.093 us; speedup 1.0000x reference)
//
#include <hip/hip_runtime.h>
#include <math.h>

#define BB 8
#define NN 1024
#define HH 32
#define II 192   // K * C = 3*64
#define DD 16
#define BN (BB*NN)

typedef __attribute__((ext_vector_type(8))) short short8v;   // 8 bf16 (4 VGPRs)
typedef __attribute__((ext_vector_type(4))) float float4v;   // MFMA C/D

union Frag8 { short8v v; uint2 u[2]; };

// fp32 -> bf16 round-to-nearest-even (finite inputs)
static __device__ inline ushort bf(float x) {
  union { float f; unsigned u; } c; c.f = x;
  unsigned r = c.u + 0x7FFFu + ((c.u >> 16) & 1u);
  return (ushort)(r >> 16);
}

// ---------------------------------------------------------------------------
// build x_g columns [0:64): x_g[:,0:32)=cur, x_g[:,32:64)= state (or z*state)
// ---------------------------------------------------------------------------
__global__ __launch_bounds__(256) void build_xg(
    const float* __restrict__ cur,    // [BN,32]
    const float* __restrict__ state,  // [BN,32]
    const float* __restrict__ zr,     // [BN,64] or nullptr; uses z = zr[:, :32]
    float* __restrict__ xg)           // [BN,192]
{
  int idx = blockIdx.x * 256 + threadIdx.x;   // over BN*32
  int bn = idx >> 5, c = idx & 31;
  float av = cur[idx];
  float sv = state[idx];
  if (zr) sv *= zr[(size_t)bn * 64 + c];
  xg[(size_t)bn * II + c] = av;
  xg[(size_t)bn * II + 32 + c] = sv;
}

// ---------------------------------------------------------------------------
// propagation GEMM, M-tile 32, K-step 64, register-prefetch double buffer.
//   acc[m, c] = sum_k S[m,k] * xg[b,k, co_in + c]   (c in 0..63)
// mode 0: xg[b,m,co_out+c] = acc
// mode 1: xg[b,m,co_out+c] = 2*acc - xg[b,m,c]   (Chebyshev T2)
// ---------------------------------------------------------------------------
__global__ __launch_bounds__(256) void prop_gemm(
    const float* __restrict__ S,
    float* __restrict__ xg,
    int co_in, int co_out, int mode)
{
  __shared__ float sS[32][68];   // [row][k]; 68: 16B-aligned rows + bank rotate
  __shared__ float sX[64][64];   // [k][col]
  const int b = blockIdx.y;
  const int m0 = blockIdx.x * 32;
  float* xgb = xg + (size_t)b * NN * II;
  const int tid = threadIdx.x;
  const int tx = tid & 15, ty = tid >> 4;
  float acc[2][4] = {};

  float4 pS[2], pX[4];
  // S tile 32x64 = 512 float4 (2/thread): row=f>>4, k4=(f&15)*4
  // X tile 64x64 = 1024 float4 (4/thread): k=f>>4, c4=(f&15)*4
#define LOAD_TILES(k0)                                                        \
  {                                                                           \
    _Pragma("unroll")                                                         \
    for (int q = 0; q < 2; ++q) {                                             \
      int f = tid + q * 256;                                                  \
      pS[q] = *(const float4*)(S + (size_t)(m0 + (f >> 4)) * NN + (k0) +      \
                               ((f & 15) << 2));                              \
    }                                                                         \
    _Pragma("unroll")                                                         \
    for (int q = 0; q < 4; ++q) {                                             \
      int f = tid + q * 256;                                                  \
      pX[q] = *(const float4*)(xgb + (size_t)((k0) + (f >> 4)) * II + co_in + \
                               ((f & 15) << 2));                              \
    }                                                                         \
  }

  LOAD_TILES(0)
  for (int k0 = 0; k0 < NN; k0 += 64) {
    __syncthreads();   // previous compute done; LDS reusable
#pragma unroll
    for (int q = 0; q < 2; ++q) {
      int f = tid + q * 256;
      *(float4*)&sS[f >> 4][(f & 15) << 2] = pS[q];
    }
#pragma unroll
    for (int q = 0; q < 4; ++q) {
      int f = tid + q * 256;
      *(float4*)&sX[f >> 4][(f & 15) << 2] = pX[q];
    }
    __syncthreads();   // LDS tiles ready
    if (k0 + 64 < NN) LOAD_TILES(k0 + 64)   // overlap next loads with compute
#pragma unroll 8
    for (int kk = 0; kk < 64; ++kk) {
      float a0 = sS[ty * 2 + 0][kk];
      float a1 = sS[ty * 2 + 1][kk];
      float4 b4 = *(const float4*)&sX[kk][tx * 4];
      acc[0][0] += a0 * b4.x; acc[0][1] += a0 * b4.y; acc[0][2] += a0 * b4.z; acc[0][3] += a0 * b4.w;
      acc[1][0] += a1 * b4.x; acc[1][1] += a1 * b4.y; acc[1][2] += a1 * b4.z; acc[1][3] += a1 * b4.w;
    }
  }
#undef LOAD_TILES

#pragma unroll
  for (int j = 0; j < 2; ++j) {
    int row = m0 + ty * 2 + j;
    float* dst = xgb + (size_t)row * II + co_out + tx * 4;
    if (mode == 0) {
      dst[0] = acc[j][0]; dst[1] = acc[j][1]; dst[2] = acc[j][2]; dst[3] = acc[j][3];
    } else {
      const float* x0 = xgb + (size_t)row * II + tx * 4;
      dst[0] = 2.f * acc[j][0] - x0[0];
      dst[1] = 2.f * acc[j][1] - x0[1];
      dst[2] = 2.f * acc[j][2] - x0[2];
      dst[3] = 2.f * acc[j][3] - x0[3];
    }
  }
}

// ---------------------------------------------------------------------------
// weight prep: W[d][i][o] f32  ->  Wt[d][o][i] bf16   (one block per d)
// ---------------------------------------------------------------------------
template <int O>
__global__ __launch_bounds__(256) void prep_w(
    const float* __restrict__ W,
    ushort* __restrict__ Wt)
{
  __shared__ float lds[II][O + 1];
  const int d = blockIdx.x;
  const float* Wd = W + (size_t)d * II * O;
  ushort* Wtd = Wt + (size_t)d * O * II;
  const int tid = threadIdx.x;
  for (int f = tid; f < II * O / 4; f += 256) {   // coalesced f32 loads
    int i = f / (O / 4);
    int o4 = (f % (O / 4)) * 4;
    float4 v = *(const float4*)(Wd + (size_t)i * O + o4);
    lds[i][o4 + 0] = v.x; lds[i][o4 + 1] = v.y;
    lds[i][o4 + 2] = v.z; lds[i][o4 + 3] = v.w;
  }
  __syncthreads();
  for (int h = tid; h < II * O / 2; h += 256) {   // coalesced bf16-pair stores
    int o = h / (II / 2);
    int i2 = (h % (II / 2)) * 2;
    unsigned p = (unsigned)bf(lds[i2][o]) | ((unsigned)bf(lds[i2 + 1][o]) << 16);
    *(unsigned*)(Wtd + (size_t)o * II + i2) = p;
  }
}

// ---------------------------------------------------------------------------
// MFMA meta contraction, fused activation/GRU epilogue.
//   out[m,o] = act( sum_d emb[m,d] * ( (xg[m,:] @ W[d])[o] + bias[d,o] ) )
// Block: 128 threads (2 waves), M-tile 32 (wave w -> rows w*16..w*16+15).
// ---------------------------------------------------------------------------
template <int O, int MODE>
__global__ __launch_bounds__(128) void contract_mfma(
    const float* __restrict__ xg,     // [BN,192]
    const float* __restrict__ emb,    // [BN,16]
    const ushort* __restrict__ Wt,    // [16][O][192] bf16
    const float* __restrict__ bias,   // [16][O]
    const float* __restrict__ zr_in,  // [BN,64]  (MODE 1)
    const float* __restrict__ state,  // [BN,32]  (MODE 1)
    float* __restrict__ out0,
    float* __restrict__ out1)         // may be null
{
  constexpr int NF = O / 16;                  // col fragments per wave
  __shared__ ushort A_lds[32][200];
  __shared__ ushort B_lds[O][200];
  __shared__ float emb_lds[32][17];
  __shared__ float bias_lds[16][O];

  const int bn0 = blockIdx.x * 32;
  const int tid = threadIdx.x;
  const int w = tid >> 6;                     // wave 0/1
  const int l = tid & 63;
  const int l15 = l & 15, l4 = l >> 4;

  // ---- stage A: xg[bn0..bn0+31][0..191] -> bf16
#pragma unroll
  for (int q = 0; q < 12; ++q) {              // 1536 float4 chunks
    int f = tid + q * 128;
    int row = f / 48;
    int k4 = (f % 48) * 4;
    float4 v = *(const float4*)(xg + (size_t)(bn0 + row) * II + k4);
    ushort4 b4; b4.x = bf(v.x); b4.y = bf(v.y); b4.z = bf(v.z); b4.w = bf(v.w);
    *(ushort4*)&A_lds[row][k4] = b4;
  }
  // ---- stage emb [32][16]
  {
    int row = tid / 4, d4 = (tid % 4) * 4;
    float4 v = *(const float4*)(emb + (size_t)(bn0 + row) * DD + d4);
    emb_lds[row][d4 + 0] = v.x; emb_lds[row][d4 + 1] = v.y;
    emb_lds[row][d4 + 2] = v.z; emb_lds[row][d4 + 3] = v.w;
  }
  // ---- stage bias [16][O]
  for (int f = tid; f < DD * O / 4; f += 128) {
    int d = f / (O / 4), o4 = (f % (O / 4)) * 4;
    *(float4*)&bias_lds[d][o4] = *(const float4*)(bias + (size_t)d * O + o4);
  }

  float4v outacc[NF];
#pragma unroll
  for (int f = 0; f < NF; ++f) outacc[f] = (float4v){0.f, 0.f, 0.f, 0.f};

  const int arow = w * 16 + l15;
  const int erow = w * 16 + l4 * 4;

  for (int d = 0; d < DD; ++d) {
    __syncthreads();   // d=0: staging done; d>0: all waves done reading B_lds
    // ---- stage B = Wt[d] : [O][192] bf16, 16B chunks, coalesced
    const ushort* Wtd = Wt + (size_t)d * O * II;
#pragma unroll
    for (int q = 0; q < (O * II / 8) / 128; ++q) {
      int f = tid + q * 128;
      int o = f / 24;
      int k8 = (f % 24) * 8;
      uint4 v = *(const uint4*)(Wtd + (size_t)o * II + k8);
      *(uint4*)&B_lds[o][k8] = v;
    }
    __syncthreads();

    float4v acc[NF];
#pragma unroll
    for (int f = 0; f < NF; ++f) acc[f] = (float4v){0.f, 0.f, 0.f, 0.f};
#pragma unroll
    for (int ks = 0; ks < 6; ++ks) {
      int kb = ks * 32 + l4 * 4;
      Frag8 af;
      af.u[0] = *(const uint2*)&A_lds[arow][kb];
      af.u[1] = *(const uint2*)&A_lds[arow][kb + 16];
#pragma unroll
      for (int f = 0; f < NF; ++f) {
        Frag8 bfr;
        bfr.u[0] = *(const uint2*)&B_lds[l15 + 16 * f][kb];
        bfr.u[1] = *(const uint2*)&B_lds[l15 + 16 * f][kb + 16];
        acc[f] = __builtin_amdgcn_mfma_f32_16x16x32_bf16(af.v, bfr.v, acc[f], 0, 0, 0);
      }
    }
    // ---- fold: out += emb[row,d] * (acc + bias[d,col])
    float e0 = emb_lds[erow + 0][d];
    float e1 = emb_lds[erow + 1][d];
    float e2 = emb_lds[erow + 2][d];
    float e3 = emb_lds[erow + 3][d];
#pragma unroll
    for (int f = 0; f < NF; ++f) {
      float bb = bias_lds[d][l15 + 16 * f];
      outacc[f][0] += e0 * (acc[f][0] + bb);
      outacc[f][1] += e1 * (acc[f][1] + bb);
      outacc[f][2] += e2 * (acc[f][2] + bb);
      outacc[f][3] += e3 * (acc[f][3] + bb);
    }
  }

  // ---- fused epilogue
#pragma unroll
  for (int f = 0; f < NF; ++f) {
#pragma unroll
    for (int r = 0; r < 4; ++r) {
      int m = bn0 + erow + r;
      int col = l15 + 16 * f;
      float v = outacc[f][r];
      if (MODE == 0) {
        out0[(size_t)m * 64 + col] = 1.f / (1.f + __expf(-v));
      } else {
        float hc = tanhf(v);
        float rg = zr_in[(size_t)m * 64 + 32 + col];
        float st = state[(size_t)m * HH + col];
        float res = rg * st + (1.f - rg) * hc;
        out0[(size_t)m * HH + col] = res;
        if (out1) out1[(size_t)m * HH + col] = res;
      }
    }
  }
}

// ---------------------------------------------------------------------------
extern "C" void kernel_launch(void* const* d_in, const int* in_sizes, int n_in,
                              void* d_out, int out_size, void* d_ws, size_t ws_size,
                              hipStream_t stream)
{
  const float* xt         = (const float*)d_in[0];
  const float* init_state = (const float*)d_in[1];
  const float* S          = (const float*)d_in[2];
  const float* emb        = (const float*)d_in[3];

  float* out    = (float*)d_out;          // [BN,32] final cur
  float* hidden = out + (size_t)BN * HH;  // [2, BN, 32]

  float* xg = (float*)d_ws;                      // [BN,192] f32   6.0 MB
  float* zr = xg + (size_t)BN * II;              // [BN,64]  f32   2.0 MB
  ushort* wtg0 = (ushort*)(zr + (size_t)BN * 64);  // bf16 weights  1.2 MB
  ushort* wtu0 = wtg0 + (size_t)DD * II * 64;
  ushort* wtg1 = wtu0 + (size_t)DD * II * 32;
  ushort* wtu1 = wtg1 + (size_t)DD * II * 64;

  // weight prep (static inputs; recomputed every call for determinism)
  prep_w<64><<<DD, 256, 0, stream>>>((const float*)d_in[4], wtg0);
  prep_w<32><<<DD, 256, 0, stream>>>((const float*)d_in[6], wtu0);
  prep_w<64><<<DD, 256, 0, stream>>>((const float*)d_in[8], wtg1);
  prep_w<32><<<DD, 256, 0, stream>>>((const float*)d_in[10], wtu1);

  const float* cur = xt;
  for (int l = 0; l < 2; ++l) {
    const float* state = init_state + (size_t)l * BN * HH;
    const float* gb = (const float*)d_in[5 + 4 * l];
    const float* ub = (const float*)d_in[7 + 4 * l];
    const ushort* wtg = (l == 0) ? wtg0 : wtg1;
    const ushort* wtu = (l == 0) ? wtu0 : wtu1;
    float* hid = hidden + (size_t)l * BN * HH;

    dim3 pg(NN / 32, BB);   // 32 x 8 = 256 blocks
    // gate gconv: inp = [cur, state]
    build_xg<<<BN * 32 / 256, 256, 0, stream>>>(cur, state, nullptr, xg);
    prop_gemm<<<pg, 256, 0, stream>>>(S, xg, 0, 64, 0);
    prop_gemm<<<pg, 256, 0, stream>>>(S, xg, 64, 128, 1);
    contract_mfma<64, 0><<<BN / 32, 128, 0, stream>>>(
        xg, emb, wtg, gb, nullptr, nullptr, zr, nullptr);
    // update gconv: cand = [cur, z*state]
    build_xg<<<BN * 32 / 256, 256, 0, stream>>>(cur, state, zr, xg);
    prop_gemm<<<pg, 256, 0, stream>>>(S, xg, 0, 64, 0);
    prop_gemm<<<pg, 256, 0, stream>>>(S, xg, 64, 128, 1);
    contract_mfma<32, 1><<<BN / 32, 128, 0, stream>>>(
        xg, emb, wtu, ub, zr, state, hid, (l == 1) ? out : nullptr);

    cur = hid;
  }
}

// Round 8
// 213.300 us; speedup vs baseline: 3.0853x; 3.0853x over previous
//
#include <hip/hip_runtime.h>
#include <math.h>

#define BB 8
#define NN 1024
#define HH 32
#define II 192   // K * C = 3*64
#define DD 16
#define BN (BB*NN)

typedef __attribute__((ext_vector_type(8))) short short8v;   // 8 bf16 (4 VGPRs)
typedef __attribute__((ext_vector_type(4))) float float4v;   // MFMA C/D

union Frag8 { short8v v; uint2 u[2]; };

// fp32 -> bf16 round-to-nearest-even (finite inputs)
static __device__ inline ushort bf(float x) {
  union { float f; unsigned u; } c; c.f = x;
  unsigned r = c.u + 0x7FFFu + ((c.u >> 16) & 1u);
  return (ushort)(r >> 16);
}

// ---------------------------------------------------------------------------
// build_xg MODE 0: xg[:,0:32)=cur, xg[:,32:64)=state      (gate phase)
// build_xg MODE 1: xg[:,32:64)=z*state only               (update phase)
// ---------------------------------------------------------------------------
__global__ __launch_bounds__(256) void build_xg(
    const float* __restrict__ cur,    // [BN,32]
    const float* __restrict__ state,  // [BN,32]
    const float* __restrict__ zr,     // [BN,64] (MODE 1), z = zr[:, :32]
    float* __restrict__ xg,           // [BN,192]
    int mode)
{
  int idx = blockIdx.x * 256 + threadIdx.x;   // over BN*32
  int bn = idx >> 5, c = idx & 31;
  float sv = state[idx];
  if (mode == 0) {
    xg[(size_t)bn * II + c] = cur[idx];
    xg[(size_t)bn * II + 32 + c] = sv;
  } else {
    xg[(size_t)bn * II + 32 + c] = sv * zr[(size_t)bn * 64 + c];
  }
}

// ---------------------------------------------------------------------------
// S f32 [1024][1024] -> bf16 (same layout)
// ---------------------------------------------------------------------------
__global__ __launch_bounds__(256) void prep_s(
    const float* __restrict__ S, ushort* __restrict__ Sb)
{
  int idx = blockIdx.x * 256 + threadIdx.x;   // over 1024*1024/4
  float4 v = ((const float4*)S)[idx];
  ushort4 o; o.x = bf(v.x); o.y = bf(v.y); o.z = bf(v.z); o.w = bf(v.w);
  ((ushort4*)Sb)[idx] = o;
}

// ---------------------------------------------------------------------------
// MFMA propagation: per batch b, rows m0..m0+31:
//   acc[m, c] = sum_k Sb[m,k] * xg[b, k, co_in + c]    (c in 0..NC)
// MODE 0: xg[b,m,co_out+c] = acc
// MODE 1: xg[b,m,co_out+c] = 2*acc - xg[b,m,(co_in-64)+c]   (Chebyshev T2)
// 256 threads = 4 waves: wave w -> rows (w&1)*16, cols (w>>1)*(NC/2).
// A = Sb tile [32][k] bf16; B = X^T tile [c][k] bf16 (transposed on stage).
// ---------------------------------------------------------------------------
template <int NC, int MODE>
__global__ __launch_bounds__(256) void prop_mfma(
    const ushort* __restrict__ Sb,    // [1024][1024] bf16
    float* __restrict__ xg,
    int co_in, int co_out)
{
  constexpr int NF = NC / 32;                 // col fragments per wave
  constexpr int KC = 128;                     // k-chunk
  __shared__ ushort A_lds[32][136];           // rows 16B-aligned, 2-way reads
  __shared__ ushort B_lds[NC][132];           // 264B rows: reads conflict-free

  const int b = blockIdx.y;
  const int m0 = blockIdx.x * 32;
  float* xgb = xg + (size_t)b * NN * II;
  const int tid = threadIdx.x;
  const int w = tid >> 6, l = tid & 63;
  const int l15 = l & 15, l4 = l >> 4;
  const int wr = (w & 1) * 16;                // wave row offset
  const int wc = (w >> 1) * (NC / 2);         // wave col offset

  float4v acc[NF];
#pragma unroll
  for (int f = 0; f < NF; ++f) acc[f] = (float4v){0.f, 0.f, 0.f, 0.f};

  for (int k0 = 0; k0 < NN; k0 += KC) {
    __syncthreads();   // previous chunk's reads done
    // ---- stage A: Sb[m0..m0+31][k0..k0+127]  (512 x 16B)
#pragma unroll
    for (int q = 0; q < 2; ++q) {
      int f = tid + q * 256;
      int row = f >> 4, s8 = (f & 15) * 8;
      *(uint4*)&A_lds[row][s8] =
          *(const uint4*)(Sb + (size_t)(m0 + row) * NN + k0 + s8);
    }
    // ---- stage B = X^T: xg[k0+k][co_in+c] -> B_lds[c][k], bf16 k-pairs
#pragma unroll
    for (int q = 0; q < NF * 2; ++q) {
      int u = tid + q * 256;
      int kp = u / (NC / 4);
      int c4 = (u % (NC / 4)) * 4;
      const float* p0 = xgb + (size_t)(k0 + 2 * kp) * II + co_in + c4;
      float4 f0 = *(const float4*)p0;
      float4 f1 = *(const float4*)(p0 + II);
      *(unsigned*)&B_lds[c4 + 0][2 * kp] = (unsigned)bf(f0.x) | ((unsigned)bf(f1.x) << 16);
      *(unsigned*)&B_lds[c4 + 1][2 * kp] = (unsigned)bf(f0.y) | ((unsigned)bf(f1.y) << 16);
      *(unsigned*)&B_lds[c4 + 2][2 * kp] = (unsigned)bf(f0.z) | ((unsigned)bf(f1.z) << 16);
      *(unsigned*)&B_lds[c4 + 3][2 * kp] = (unsigned)bf(f0.w) | ((unsigned)bf(f1.w) << 16);
    }
    __syncthreads();   // tiles ready
#pragma unroll
    for (int ks = 0; ks < KC / 32; ++ks) {
      int kb = ks * 32 + l4 * 4;
      Frag8 af;
      af.u[0] = *(const uint2*)&A_lds[wr + l15][kb];
      af.u[1] = *(const uint2*)&A_lds[wr + l15][kb + 16];
#pragma unroll
      for (int f = 0; f < NF; ++f) {
        Frag8 bfr;
        bfr.u[0] = *(const uint2*)&B_lds[wc + l15 + 16 * f][kb];
        bfr.u[1] = *(const uint2*)&B_lds[wc + l15 + 16 * f][kb + 16];
        acc[f] = __builtin_amdgcn_mfma_f32_16x16x32_bf16(af.v, bfr.v, acc[f], 0, 0, 0);
      }
    }
  }

  // ---- write: C frag col=l15(+16f), row=l4*4+r
#pragma unroll
  for (int f = 0; f < NF; ++f) {
#pragma unroll
    for (int r = 0; r < 4; ++r) {
      int row = m0 + wr + l4 * 4 + r;
      int col = wc + l15 + 16 * f;
      float v = acc[f][r];
      if (MODE == 1)
        v = 2.f * v - xgb[(size_t)row * II + (co_in - 64) + col];
      xgb[(size_t)row * II + co_out + col] = v;
    }
  }
}

// ---------------------------------------------------------------------------
// weight prep: W[d][i][o] f32  ->  Wt[d][o][i] bf16   (one block per d)
// ---------------------------------------------------------------------------
template <int O>
__global__ __launch_bounds__(256) void prep_w(
    const float* __restrict__ W,
    ushort* __restrict__ Wt)
{
  __shared__ float lds[II][O + 1];
  const int d = blockIdx.x;
  const float* Wd = W + (size_t)d * II * O;
  ushort* Wtd = Wt + (size_t)d * O * II;
  const int tid = threadIdx.x;
  for (int f = tid; f < II * O / 4; f += 256) {
    int i = f / (O / 4);
    int o4 = (f % (O / 4)) * 4;
    float4 v = *(const float4*)(Wd + (size_t)i * O + o4);
    lds[i][o4 + 0] = v.x; lds[i][o4 + 1] = v.y;
    lds[i][o4 + 2] = v.z; lds[i][o4 + 3] = v.w;
  }
  __syncthreads();
  for (int h = tid; h < II * O / 2; h += 256) {
    int o = h / (II / 2);
    int i2 = (h % (II / 2)) * 2;
    unsigned p = (unsigned)bf(lds[i2][o]) | ((unsigned)bf(lds[i2 + 1][o]) << 16);
    *(unsigned*)(Wtd + (size_t)o * II + i2) = p;
  }
}

// ---------------------------------------------------------------------------
// MFMA meta contraction, fused activation/GRU epilogue (unchanged from R5).
// ---------------------------------------------------------------------------
template <int O, int MODE>
__global__ __launch_bounds__(128) void contract_mfma(
    const float* __restrict__ xg,     // [BN,192]
    const float* __restrict__ emb,    // [BN,16]
    const ushort* __restrict__ Wt,    // [16][O][192] bf16
    const float* __restrict__ bias,   // [16][O]
    const float* __restrict__ zr_in,  // [BN,64]  (MODE 1)
    const float* __restrict__ state,  // [BN,32]  (MODE 1)
    float* __restrict__ out0,
    float* __restrict__ out1)         // may be null
{
  constexpr int NF = O / 16;
  __shared__ ushort A_lds[32][200];
  __shared__ ushort B_lds[O][200];
  __shared__ float emb_lds[32][17];
  __shared__ float bias_lds[16][O];

  const int bn0 = blockIdx.x * 32;
  const int tid = threadIdx.x;
  const int w = tid >> 6;
  const int l = tid & 63;
  const int l15 = l & 15, l4 = l >> 4;

#pragma unroll
  for (int q = 0; q < 12; ++q) {
    int f = tid + q * 128;
    int row = f / 48;
    int k4 = (f % 48) * 4;
    float4 v = *(const float4*)(xg + (size_t)(bn0 + row) * II + k4);
    ushort4 b4; b4.x = bf(v.x); b4.y = bf(v.y); b4.z = bf(v.z); b4.w = bf(v.w);
    *(ushort4*)&A_lds[row][k4] = b4;
  }
  {
    int row = tid / 4, d4 = (tid % 4) * 4;
    float4 v = *(const float4*)(emb + (size_t)(bn0 + row) * DD + d4);
    emb_lds[row][d4 + 0] = v.x; emb_lds[row][d4 + 1] = v.y;
    emb_lds[row][d4 + 2] = v.z; emb_lds[row][d4 + 3] = v.w;
  }
  for (int f = tid; f < DD * O / 4; f += 128) {
    int d = f / (O / 4), o4 = (f % (O / 4)) * 4;
    *(float4*)&bias_lds[d][o4] = *(const float4*)(bias + (size_t)d * O + o4);
  }

  float4v outacc[NF];
#pragma unroll
  for (int f = 0; f < NF; ++f) outacc[f] = (float4v){0.f, 0.f, 0.f, 0.f};

  const int arow = w * 16 + l15;
  const int erow = w * 16 + l4 * 4;

  for (int d = 0; d < DD; ++d) {
    __syncthreads();
    const ushort* Wtd = Wt + (size_t)d * O * II;
#pragma unroll
    for (int q = 0; q < (O * II / 8) / 128; ++q) {
      int f = tid + q * 128;
      int o = f / 24;
      int k8 = (f % 24) * 8;
      *(uint4*)&B_lds[o][k8] = *(const uint4*)(Wtd + (size_t)o * II + k8);
    }
    __syncthreads();

    float4v acc[NF];
#pragma unroll
    for (int f = 0; f < NF; ++f) acc[f] = (float4v){0.f, 0.f, 0.f, 0.f};
#pragma unroll
    for (int ks = 0; ks < 6; ++ks) {
      int kb = ks * 32 + l4 * 4;
      Frag8 af;
      af.u[0] = *(const uint2*)&A_lds[arow][kb];
      af.u[1] = *(const uint2*)&A_lds[arow][kb + 16];
#pragma unroll
      for (int f = 0; f < NF; ++f) {
        Frag8 bfr;
        bfr.u[0] = *(const uint2*)&B_lds[l15 + 16 * f][kb];
        bfr.u[1] = *(const uint2*)&B_lds[l15 + 16 * f][kb + 16];
        acc[f] = __builtin_amdgcn_mfma_f32_16x16x32_bf16(af.v, bfr.v, acc[f], 0, 0, 0);
      }
    }
    float e0 = emb_lds[erow + 0][d];
    float e1 = emb_lds[erow + 1][d];
    float e2 = emb_lds[erow + 2][d];
    float e3 = emb_lds[erow + 3][d];
#pragma unroll
    for (int f = 0; f < NF; ++f) {
      float bb = bias_lds[d][l15 + 16 * f];
      outacc[f][0] += e0 * (acc[f][0] + bb);
      outacc[f][1] += e1 * (acc[f][1] + bb);
      outacc[f][2] += e2 * (acc[f][2] + bb);
      outacc[f][3] += e3 * (acc[f][3] + bb);
    }
  }

#pragma unroll
  for (int f = 0; f < NF; ++f) {
#pragma unroll
    for (int r = 0; r < 4; ++r) {
      int m = bn0 + erow + r;
      int col = l15 + 16 * f;
      float v = outacc[f][r];
      if (MODE == 0) {
        out0[(size_t)m * 64 + col] = 1.f / (1.f + __expf(-v));
      } else {
        float hc = tanhf(v);
        float rg = zr_in[(size_t)m * 64 + 32 + col];
        float st = state[(size_t)m * HH + col];
        float res = rg * st + (1.f - rg) * hc;
        out0[(size_t)m * HH + col] = res;
        if (out1) out1[(size_t)m * HH + col] = res;
      }
    }
  }
}

// ---------------------------------------------------------------------------
extern "C" void kernel_launch(void* const* d_in, const int* in_sizes, int n_in,
                              void* d_out, int out_size, void* d_ws, size_t ws_size,
                              hipStream_t stream)
{
  const float* xt         = (const float*)d_in[0];
  const float* init_state = (const float*)d_in[1];
  const float* S          = (const float*)d_in[2];
  const float* emb        = (const float*)d_in[3];

  float* out    = (float*)d_out;          // [BN,32] final cur
  float* hidden = out + (size_t)BN * HH;  // [2, BN, 32]

  float* xg = (float*)d_ws;                        // [BN,192] f32   6.0 MB
  float* zr = xg + (size_t)BN * II;                // [BN,64]  f32   2.0 MB
  ushort* wtg0 = (ushort*)(zr + (size_t)BN * 64);  // bf16 weights   1.5 MB
  ushort* wtu0 = wtg0 + (size_t)DD * II * 64;
  ushort* wtg1 = wtu0 + (size_t)DD * II * 32;
  ushort* wtu1 = wtg1 + (size_t)DD * II * 64;
  ushort* Sb   = wtu1 + (size_t)DD * II * 32;      // [1024][1024] bf16 2.0 MB

  // static-input prep (recomputed every call for determinism)
  prep_s<<<NN * NN / 4 / 256, 256, 0, stream>>>(S, Sb);
  prep_w<64><<<DD, 256, 0, stream>>>((const float*)d_in[4], wtg0);
  prep_w<32><<<DD, 256, 0, stream>>>((const float*)d_in[6], wtu0);
  prep_w<64><<<DD, 256, 0, stream>>>((const float*)d_in[8], wtg1);
  prep_w<32><<<DD, 256, 0, stream>>>((const float*)d_in[10], wtu1);

  const float* cur = xt;
  for (int l = 0; l < 2; ++l) {
    const float* state = init_state + (size_t)l * BN * HH;
    const float* gb = (const float*)d_in[5 + 4 * l];
    const float* ub = (const float*)d_in[7 + 4 * l];
    const ushort* wtg = (l == 0) ? wtg0 : wtg1;
    const ushort* wtu = (l == 0) ? wtu0 : wtu1;
    float* hid = hidden + (size_t)l * BN * HH;

    dim3 pg(NN / 32, BB);   // 32 x 8 = 256 blocks
    // gate gconv: inp = [cur, state]; T1 cols 64:128, T2 cols 128:192
    build_xg<<<BN * 32 / 256, 256, 0, stream>>>(cur, state, nullptr, xg, 0);
    prop_mfma<64, 0><<<pg, 256, 0, stream>>>(Sb, xg, 0, 64);
    prop_mfma<64, 1><<<pg, 256, 0, stream>>>(Sb, xg, 64, 128);
    contract_mfma<64, 0><<<BN / 32, 128, 0, stream>>>(
        xg, emb, wtg, gb, nullptr, nullptr, zr, nullptr);
    // update gconv: cand = [cur, z*state]; x-half (S@cur) columns reused,
    // only the state-half (32 cols) re-propagated.
    build_xg<<<BN * 32 / 256, 256, 0, stream>>>(cur, state, zr, xg, 1);
    prop_mfma<32, 0><<<pg, 256, 0, stream>>>(Sb, xg, 32, 96);
    prop_mfma<32, 1><<<pg, 256, 0, stream>>>(Sb, xg, 96, 160);
    contract_mfma<32, 1><<<BN / 32, 128, 0, stream>>>(
        xg, emb, wtu, ub, zr, state, hid, (l == 1) ? out : nullptr);

    cur = hid;
  }
}

// Round 9
// 189.907 us; speedup vs baseline: 3.4653x; 1.1232x over previous
//
#include <hip/hip_runtime.h>
#include <math.h>

#define BB 8
#define NN 1024
#define HH 32
#define II 192   // K * C = 3*64
#define DD 16
#define BN (BB*NN)

typedef __attribute__((ext_vector_type(8))) short short8v;   // 8 bf16 (4 VGPRs)
typedef __attribute__((ext_vector_type(4))) float float4v;   // MFMA C/D

union Frag8 { short8v v; uint2 u[2]; };

// fp32 -> bf16 round-to-nearest-even (finite inputs)
static __device__ inline ushort bf(float x) {
  union { float f; unsigned u; } c; c.f = x;
  unsigned r = c.u + 0x7FFFu + ((c.u >> 16) & 1u);
  return (ushort)(r >> 16);
}

// ---------------------------------------------------------------------------
// initial build (layer 0 gate only): xg[:,0:32)=xt, xg[:,32:64)=state
// ---------------------------------------------------------------------------
__global__ __launch_bounds__(256) void build_xg(
    const float* __restrict__ cur,    // [BN,32]
    const float* __restrict__ state,  // [BN,32]
    float* __restrict__ xg)           // [BN,192]
{
  int idx = blockIdx.x * 256 + threadIdx.x;   // over BN*32
  int bn = idx >> 5, c = idx & 31;
  xg[(size_t)bn * II + c] = cur[idx];
  xg[(size_t)bn * II + 32 + c] = state[idx];
}

// ---------------------------------------------------------------------------
// S f32 [1024][1024] -> bf16 (same layout)
// ---------------------------------------------------------------------------
__global__ __launch_bounds__(256) void prep_s(
    const float* __restrict__ S, ushort* __restrict__ Sb)
{
  int idx = blockIdx.x * 256 + threadIdx.x;   // over 1024*1024/4
  float4 v = ((const float4*)S)[idx];
  ushort4 o; o.x = bf(v.x); o.y = bf(v.y); o.z = bf(v.z); o.w = bf(v.w);
  ((ushort4*)Sb)[idx] = o;
}

// ---------------------------------------------------------------------------
// weight prep: W[d][i][o] f32 -> Wt[d][o][i] bf16. grid (DD, 2): y picks layer.
// ---------------------------------------------------------------------------
template <int O>
__global__ __launch_bounds__(256) void prep_w(
    const float* __restrict__ W0, const float* __restrict__ W1,
    ushort* __restrict__ Wt0, ushort* __restrict__ Wt1)
{
  __shared__ float lds[II][O + 1];
  const float* W = blockIdx.y ? W1 : W0;
  ushort* Wt = blockIdx.y ? Wt1 : Wt0;
  const int d = blockIdx.x;
  const float* Wd = W + (size_t)d * II * O;
  ushort* Wtd = Wt + (size_t)d * O * II;
  const int tid = threadIdx.x;
  for (int f = tid; f < II * O / 4; f += 256) {
    int i = f / (O / 4);
    int o4 = (f % (O / 4)) * 4;
    float4 v = *(const float4*)(Wd + (size_t)i * O + o4);
    lds[i][o4 + 0] = v.x; lds[i][o4 + 1] = v.y;
    lds[i][o4 + 2] = v.z; lds[i][o4 + 3] = v.w;
  }
  __syncthreads();
  for (int h = tid; h < II * O / 2; h += 256) {
    int o = h / (II / 2);
    int i2 = (h % (II / 2)) * 2;
    unsigned p = (unsigned)bf(lds[i2][o]) | ((unsigned)bf(lds[i2 + 1][o]) << 16);
    *(unsigned*)(Wtd + (size_t)o * II + i2) = p;
  }
}

// ---------------------------------------------------------------------------
// MFMA propagation: per batch b, rows m0..m0+MT-1:
//   acc[m, c] = sum_k Sb[m,k] * xg[b, k, co_in + c]    (c in 0..NC)
// MODE 0: xg[b,m,co_out+c] = acc
// MODE 1: xg[b,m,co_out+c] = 2*acc - xg[b,m,(co_in-64)+c]   (Chebyshev T2)
// NC=64: MT=16, grid (64,8)=512 blocks (2/CU); wave w -> cols w*16.
// NC=32: MT=32, grid (32,8)=256 blocks; wave w -> rows (w&1)*16, cols (w>>1)*16.
// ---------------------------------------------------------------------------
template <int NC, int MODE>
__global__ __launch_bounds__(256) void prop_mfma(
    const ushort* __restrict__ Sb,    // [1024][1024] bf16
    float* __restrict__ xg,
    int co_in, int co_out)
{
  constexpr int MT = (NC == 64) ? 16 : 32;    // row tile
  constexpr int KC = 128;                     // k-chunk
  __shared__ ushort A_lds[MT][136];
  __shared__ ushort B_lds[NC][132];

  const int b = blockIdx.y;
  const int m0 = blockIdx.x * MT;
  float* xgb = xg + (size_t)b * NN * II;
  const int tid = threadIdx.x;
  const int w = tid >> 6, l = tid & 63;
  const int l15 = l & 15, l4 = l >> 4;
  const int wr = (NC == 64) ? 0 : (w & 1) * 16;
  const int wc = (NC == 64) ? w * 16 : (w >> 1) * 16;

  float4v acc = (float4v){0.f, 0.f, 0.f, 0.f};

  for (int k0 = 0; k0 < NN; k0 += KC) {
    __syncthreads();   // previous chunk's reads done
    // ---- stage A: Sb[m0..][k0..k0+127]  (MT*8 x 16B)
#pragma unroll
    for (int q = 0; q < MT / 16; ++q) {
      int f = tid + q * 256;
      int row = f >> 4, s8 = (f & 15) * 8;
      *(uint4*)&A_lds[row][s8] =
          *(const uint4*)(Sb + (size_t)(m0 + row) * NN + k0 + s8);
    }
    // ---- stage B = X^T: xg[k0+k][co_in+c] -> B_lds[c][k], bf16 k-pairs
#pragma unroll
    for (int q = 0; q < NC / 16; ++q) {
      int u = tid + q * 256;
      int kp = u / (NC / 4);
      int c4 = (u % (NC / 4)) * 4;
      const float* p0 = xgb + (size_t)(k0 + 2 * kp) * II + co_in + c4;
      float4 f0 = *(const float4*)p0;
      float4 f1 = *(const float4*)(p0 + II);
      *(unsigned*)&B_lds[c4 + 0][2 * kp] = (unsigned)bf(f0.x) | ((unsigned)bf(f1.x) << 16);
      *(unsigned*)&B_lds[c4 + 1][2 * kp] = (unsigned)bf(f0.y) | ((unsigned)bf(f1.y) << 16);
      *(unsigned*)&B_lds[c4 + 2][2 * kp] = (unsigned)bf(f0.z) | ((unsigned)bf(f1.z) << 16);
      *(unsigned*)&B_lds[c4 + 3][2 * kp] = (unsigned)bf(f0.w) | ((unsigned)bf(f1.w) << 16);
    }
    __syncthreads();   // tiles ready
#pragma unroll
    for (int ks = 0; ks < KC / 32; ++ks) {
      int kb = ks * 32 + l4 * 4;
      Frag8 af, bfr;
      af.u[0] = *(const uint2*)&A_lds[wr + l15][kb];
      af.u[1] = *(const uint2*)&A_lds[wr + l15][kb + 16];
      bfr.u[0] = *(const uint2*)&B_lds[wc + l15][kb];
      bfr.u[1] = *(const uint2*)&B_lds[wc + l15][kb + 16];
      acc = __builtin_amdgcn_mfma_f32_16x16x32_bf16(af.v, bfr.v, acc, 0, 0, 0);
    }
  }

  // ---- write: C frag col=l15, row=l4*4+r
#pragma unroll
  for (int r = 0; r < 4; ++r) {
    int row = m0 + wr + l4 * 4 + r;
    int col = wc + l15;
    float v = acc[r];
    if (MODE == 1)
      v = 2.f * v - xgb[(size_t)row * II + (co_in - 64) + col];
    xgb[(size_t)row * II + co_out + col] = v;
  }
}

// ---------------------------------------------------------------------------
// MFMA meta contraction + fused epilogues.
//   pre[m,o] = sum_d emb[m,d] * ( (xg[m,:] @ W[d])[o] + bias[d,o] )
// O=64 (MODE 0, gate): MT=16, grid BN/16=512; zr = sigmoid(pre);
//   cols<32: xg[m,32+col] = z * state[m,col]          (build for upd phase)
// O=32 (MODE 1, upd):  MT=32, grid BN/32=256; hc=tanh(pre); r=zr[:,32+o];
//   res = r*state + (1-r)*hc -> out0 (+out1); optionally build next layer's
//   xg: [0:32)=res, [32:64)=next_state.
// 256 threads = 4 waves.
// ---------------------------------------------------------------------------
template <int O, int MODE>
__global__ __launch_bounds__(256) void contract_mfma(
    float* __restrict__ xg,           // [BN,192] (read A; MODE0 writes z*state)
    const float* __restrict__ emb,    // [BN,16]
    const ushort* __restrict__ Wt,    // [16][O][192] bf16
    const float* __restrict__ bias,   // [16][O]
    const float* __restrict__ zr_io,  // MODE0: out [BN,64]; MODE1: in
    const float* __restrict__ state,  // [BN,32]
    float* __restrict__ out0,         // MODE1: hid
    float* __restrict__ out1,         // MODE1: final out (may be null)
    const float* __restrict__ nstate, // MODE1: next layer state (may be null)
    float* __restrict__ nxg)          // MODE1: next layer xg build (may be null)
{
  constexpr int MT = (O == 64) ? 16 : 32;
  __shared__ ushort A_lds[MT][200];
  __shared__ ushort B_lds[O][200];
  __shared__ float emb_lds[MT][17];
  __shared__ float bias_lds[16][O];

  const int bn0 = blockIdx.x * MT;
  const int tid = threadIdx.x;
  const int w = tid >> 6;
  const int l = tid & 63;
  const int l15 = l & 15, l4 = l >> 4;
  const int wr = (O == 64) ? 0 : (w & 1) * 16;
  const int wc = (O == 64) ? w * 16 : (w >> 1) * 16;

  // ---- stage A: xg[bn0..bn0+MT-1][0..191] -> bf16
#pragma unroll
  for (int q = 0; q < MT * 48 / 256; ++q) {
    int f = tid + q * 256;
    int row = f / 48;
    int k4 = (f % 48) * 4;
    float4 v = *(const float4*)(xg + (size_t)(bn0 + row) * II + k4);
    ushort4 b4; b4.x = bf(v.x); b4.y = bf(v.y); b4.z = bf(v.z); b4.w = bf(v.w);
    *(ushort4*)&A_lds[row][k4] = b4;
  }
  // ---- stage emb [MT][16]
  if (tid < MT * 4) {
    int row = tid / 4, d4 = (tid % 4) * 4;
    float4 v = *(const float4*)(emb + (size_t)(bn0 + row) * DD + d4);
    emb_lds[row][d4 + 0] = v.x; emb_lds[row][d4 + 1] = v.y;
    emb_lds[row][d4 + 2] = v.z; emb_lds[row][d4 + 3] = v.w;
  }
  // ---- stage bias [16][O]
  for (int f = tid; f < DD * O / 4; f += 256) {
    int d = f / (O / 4), o4 = (f % (O / 4)) * 4;
    *(float4*)&bias_lds[d][o4] = *(const float4*)(bias + (size_t)d * O + o4);
  }

  float4v outacc = (float4v){0.f, 0.f, 0.f, 0.f};
  const int arow = wr + l15;
  const int erow = wr + l4 * 4;
  const int col = wc + l15;

  for (int d = 0; d < DD; ++d) {
    __syncthreads();   // d=0: staging done; d>0: all waves done reading B_lds
    const ushort* Wtd = Wt + (size_t)d * O * II;
#pragma unroll
    for (int q = 0; q < O * 24 / 256; ++q) {
      int f = tid + q * 256;
      int o = f / 24;
      int k8 = (f % 24) * 8;
      *(uint4*)&B_lds[o][k8] = *(const uint4*)(Wtd + (size_t)o * II + k8);
    }
    __syncthreads();

    float4v acc = (float4v){0.f, 0.f, 0.f, 0.f};
#pragma unroll
    for (int ks = 0; ks < 6; ++ks) {
      int kb = ks * 32 + l4 * 4;
      Frag8 af, bfr;
      af.u[0] = *(const uint2*)&A_lds[arow][kb];
      af.u[1] = *(const uint2*)&A_lds[arow][kb + 16];
      bfr.u[0] = *(const uint2*)&B_lds[col][kb];
      bfr.u[1] = *(const uint2*)&B_lds[col][kb + 16];
      acc = __builtin_amdgcn_mfma_f32_16x16x32_bf16(af.v, bfr.v, acc, 0, 0, 0);
    }
    float bb = bias_lds[d][col];
    outacc[0] += emb_lds[erow + 0][d] * (acc[0] + bb);
    outacc[1] += emb_lds[erow + 1][d] * (acc[1] + bb);
    outacc[2] += emb_lds[erow + 2][d] * (acc[2] + bb);
    outacc[3] += emb_lds[erow + 3][d] * (acc[3] + bb);
  }

  // ---- fused epilogue
#pragma unroll
  for (int r = 0; r < 4; ++r) {
    int m = bn0 + erow + r;
    float v = outacc[r];
    if (MODE == 0) {
      float zv = 1.f / (1.f + __expf(-v));
      ((float*)zr_io)[(size_t)m * 64 + col] = zv;
      if (col < 32)   // build upd-phase xg: z*state
        xg[(size_t)m * II + 32 + col] = zv * state[(size_t)m * HH + col];
    } else {
      float hc = tanhf(v);
      float rg = zr_io[(size_t)m * 64 + 32 + col];
      float st = state[(size_t)m * HH + col];
      float res = rg * st + (1.f - rg) * hc;
      out0[(size_t)m * HH + col] = res;
      if (out1) out1[(size_t)m * HH + col] = res;
      if (nxg) {      // build next layer's gate xg
        nxg[(size_t)m * II + col] = res;
        nxg[(size_t)m * II + 32 + col] = nstate[(size_t)m * HH + col];
      }
    }
  }
}

// ---------------------------------------------------------------------------
extern "C" void kernel_launch(void* const* d_in, const int* in_sizes, int n_in,
                              void* d_out, int out_size, void* d_ws, size_t ws_size,
                              hipStream_t stream)
{
  const float* xt         = (const float*)d_in[0];
  const float* init_state = (const float*)d_in[1];
  const float* S          = (const float*)d_in[2];
  const float* emb        = (const float*)d_in[3];

  float* out    = (float*)d_out;          // [BN,32] final cur
  float* hidden = out + (size_t)BN * HH;  // [2, BN, 32]

  float* xg = (float*)d_ws;                        // [BN,192] f32   6.0 MB
  float* zr = xg + (size_t)BN * II;                // [BN,64]  f32   2.0 MB
  ushort* wtg0 = (ushort*)(zr + (size_t)BN * 64);  // bf16 weights   1.5 MB
  ushort* wtu0 = wtg0 + (size_t)DD * II * 64;
  ushort* wtg1 = wtu0 + (size_t)DD * II * 32;
  ushort* wtu1 = wtg1 + (size_t)DD * II * 64;
  ushort* Sb   = wtu1 + (size_t)DD * II * 32;      // [1024][1024] bf16 2.0 MB

  // static-input prep (recomputed every call for determinism)
  prep_s<<<NN * NN / 4 / 256, 256, 0, stream>>>(S, Sb);
  prep_w<64><<<dim3(DD, 2), 256, 0, stream>>>(
      (const float*)d_in[4], (const float*)d_in[8], wtg0, wtg1);
  prep_w<32><<<dim3(DD, 2), 256, 0, stream>>>(
      (const float*)d_in[6], (const float*)d_in[10], wtu0, wtu1);

  build_xg<<<BN * 32 / 256, 256, 0, stream>>>(xt, init_state, xg);

  for (int l = 0; l < 2; ++l) {
    const float* state = init_state + (size_t)l * BN * HH;
    const float* gb = (const float*)d_in[5 + 4 * l];
    const float* ub = (const float*)d_in[7 + 4 * l];
    const ushort* wtg = (l == 0) ? wtg0 : wtg1;
    const ushort* wtu = (l == 0) ? wtu0 : wtu1;
    float* hid = hidden + (size_t)l * BN * HH;

    // gate gconv: inp = [cur, state] in xg[0:64); T1 -> 64:128, T2 -> 128:192
    prop_mfma<64, 0><<<dim3(NN / 16, BB), 256, 0, stream>>>(Sb, xg, 0, 64);
    prop_mfma<64, 1><<<dim3(NN / 16, BB), 256, 0, stream>>>(Sb, xg, 64, 128);
    contract_mfma<64, 0><<<BN / 16, 256, 0, stream>>>(
        xg, emb, wtg, gb, zr, state, nullptr, nullptr, nullptr, nullptr);
    // upd gconv: cand = [cur, z*state]; reuse S@cur (64:96) and T2cur (128:160);
    // re-propagate only the state half: T1 -> 96:128, T2 -> 160:192.
    prop_mfma<32, 0><<<dim3(NN / 32, BB), 256, 0, stream>>>(Sb, xg, 32, 96);
    prop_mfma<32, 1><<<dim3(NN / 32, BB), 256, 0, stream>>>(Sb, xg, 96, 160);
    contract_mfma<32, 1><<<BN / 32, 256, 0, stream>>>(
        xg, emb, wtu, ub, zr, state, hid, (l == 1) ? out : nullptr,
        (l == 0) ? init_state + (size_t)BN * HH : nullptr,
        (l == 0) ? xg : nullptr);
  }
}